// Round 1
// baseline (645.874 us; speedup 1.0000x reference)
//
#include <hip/hip_runtime.h>

#define EPSV 1e-5f
#define HP 130            // padded H/W
#define HW 16384          // 128*128

typedef unsigned int u32;
typedef unsigned short bfu;                                    // bf16 storage
typedef __bf16 bf16x8 __attribute__((ext_vector_type(8)));
typedef float  f32x4  __attribute__((ext_vector_type(4)));

__device__ __forceinline__ bfu f2bf(float f){
  u32 u = __builtin_bit_cast(u32, f);
  return (bfu)((u + 0x7FFFu + ((u >> 16) & 1u)) >> 16);        // RNE
}
__device__ __forceinline__ float bf2f(bfu h){
  return __builtin_bit_cast(float, ((u32)h) << 16);
}
__device__ __forceinline__ f32x4 mfma16(bf16x8 a, bf16x8 b, f32x4 c){
  return __builtin_amdgcn_mfma_f32_16x16x32_bf16(a, b, c, 0, 0, 0);
}
__device__ __forceinline__ bf16x8 ldsfrag(const bfu* p){
  return __builtin_bit_cast(bf16x8, *(const uint4*)p);
}

// ---------------- prep kernels ----------------

// zero w11T + out3T (contiguous 17,305,600 B)
__global__ void k_zero(uint4* p, int n4){
  uint4 z = {0,0,0,0};
  for (int i = blockIdx.x*256 + threadIdx.x; i < n4; i += gridDim.x*256) p[i] = z;
}

// weight reorders -> bf16.  A11[tap][och128][cin128]; A12[t][tap2][c64][j64]; A3[tap2][oc64][j64]
__global__ void k_prep_w(const float* __restrict__ w11w, const float* __restrict__ w21w,
                         const float* __restrict__ w12w, const float* __restrict__ w3w,
                         bfu* A11, bfu* A12, bfu* A3){
  const int total = 147456 + 331776 + 36864;
  for (int i = blockIdx.x*256 + threadIdx.x; i < total; i += gridDim.x*256){
    float v; bfu* dst;
    if (i < 147456){
      int tap = i >> 14, och = (i >> 7) & 127, cin = i & 127;
      v = (och < 64) ? w11w[(och*128 + cin)*9 + tap] : w21w[((och-64)*128 + cin)*9 + tap];
      dst = A11 + i;
    } else if (i < 147456 + 331776){
      int i2 = i - 147456;
      int g = i2 >> 12, t = g/9, tap2 = g%9;
      int c = (i2 >> 6) & 63, j = i2 & 63;
      v = w12w[((c*9 + t)*64 + j)*9 + tap2];
      dst = A12 + i2;
    } else {
      int i3 = i - (147456 + 331776);
      int tap2 = i3 >> 12, oc = (i3 >> 6) & 63, j = i3 & 63;
      v = w3w[(oc*64 + j)*9 + tap2];
      dst = A3 + i3;
    }
    *dst = f2bf(v);
  }
}

// catT: NHWC bf16 with zero border: [b][130][130][128ch] (ch<64: input, else weight)
__global__ void k_prep_cat(const float* __restrict__ inp, const float* __restrict__ wgt, bfu* catT){
  const int total = 4*HP*HP*128;
  for (int i = blockIdx.x*256 + threadIdx.x; i < total; i += gridDim.x*256){
    int ch = i & 127; int pix = i >> 7;
    int wp = pix % 130; int hp = (pix/130) % 130; int b = pix/(130*130);
    float v = 0.f;
    if (hp >= 1 && hp <= 128 && wp >= 1 && wp <= 128){
      int h = hp-1, w = wp-1;
      v = (ch < 64) ? inp[((b*64 + ch)*128 + h)*128 + w]
                    : wgt[((b*64 + ch-64)*128 + h)*128 + w];
    }
    catT[i] = f2bf(v);
  }
}

// ---------------- k1: conv11 + conv21 (implicit GEMM, M=128, K=9*128) ----------------
// block: 256 thr = 4 waves (2m x 2n); tile 8x16 pixels; cat tile 10x18 cells x 272B in LDS
__global__ __launch_bounds__(256) void k1_conv(
    const bfu* __restrict__ catT, const bfu* __restrict__ A11,
    const float* __restrict__ b11, const float* __restrict__ b21,
    bfu* __restrict__ w11T, float* __restrict__ poolP){
  __shared__ bfu lds[24480];                 // 180 cells * 136 u16 (272B, 17x16B slots)
  int tid = threadIdx.x;
  int b = blockIdx.y, tile = blockIdx.x;     // 0..127
  int h0 = (tile >> 3)*8, w0 = (tile & 7)*16;

  const uint4* catT4 = (const uint4*)catT;
  for (int s = tid; s < 180*17; s += 256){
    int cell = s/17, sub = s%17;
    if (sub < 16){
      int th = cell/18, tw = cell%18;
      uint4 v = catT4[(((b*HP + h0+th)*HP) + (w0+tw))*16 + sub];
      *(uint4*)&lds[cell*136 + sub*8] = v;
    }
  }
  __syncthreads();

  int wid = tid >> 6, l = tid & 63, lg = l >> 4, pc = l & 15;
  int wm = wid >> 1, wn = wid & 1;
  f32x4 acc[4][4];
  #pragma unroll
  for (int i = 0; i < 4; ++i)
    #pragma unroll
    for (int j = 0; j < 4; ++j) acc[i][j] = f32x4{0.f,0.f,0.f,0.f};

  const uint4* A4 = (const uint4*)A11;
  #pragma unroll 1
  for (int tap = 0; tap < 9; ++tap){
    int kh = tap/3, kw = tap%3;
    #pragma unroll
    for (int jc = 0; jc < 4; ++jc){
      bf16x8 a[4], bb[4];
      #pragma unroll
      for (int fm = 0; fm < 4; ++fm){
        int row = wm*64 + fm*16 + pc;
        a[fm] = __builtin_bit_cast(bf16x8, A4[(tap*128 + row)*16 + jc*4 + lg]);
      }
      #pragma unroll
      for (int fn = 0; fn < 4; ++fn){
        int cell = (wn*4 + fn + kh)*18 + (pc + kw);
        bb[fn] = ldsfrag(&lds[cell*136 + jc*32 + lg*8]);
      }
      #pragma unroll
      for (int fm = 0; fm < 4; ++fm)
        #pragma unroll
        for (int fn = 0; fn < 4; ++fn)
          acc[fm][fn] = mfma16(a[fm], bb[fn], acc[fm][fn]);
    }
  }
  __syncthreads();

  if (wm == 0){                              // w11 path: relu(acc+bias) -> LDS transpose
    #pragma unroll
    for (int fm = 0; fm < 4; ++fm)
      #pragma unroll
      for (int r = 0; r < 4; ++r){
        int och = fm*16 + lg*4 + r;
        float bias = b11[och];
        #pragma unroll
        for (int fn = 0; fn < 4; ++fn){
          float v = acc[fm][fn][r] + bias;
          v = v > 0.f ? v : 0.f;
          int px = wn*64 + fn*16 + pc;
          lds[px*72 + och] = f2bf(v);
        }
      }
  } else {                                   // w21 path: pooled partial sums only
    float* statsF = (float*)&lds[20000];
    #pragma unroll
    for (int fm = 0; fm < 4; ++fm)
      #pragma unroll
      for (int r = 0; r < 4; ++r){
        int cw = fm*16 + lg*4 + r;
        float bias = b21[cw];
        float s = 0.f;
        #pragma unroll
        for (int fn = 0; fn < 4; ++fn){
          float v = acc[fm][fn][r] + bias;
          s += (v > 0.f ? v : 0.f);
        }
        s += __shfl_xor(s,1); s += __shfl_xor(s,2); s += __shfl_xor(s,4); s += __shfl_xor(s,8);
        if (pc == 0) statsF[wn*64 + cw] = s;
      }
  }
  __syncthreads();

  if (wid < 2){                              // NHWC write of w11 (bf16, padded dst)
    int px = tid;                            // 0..127
    int h = h0 + (px >> 4), w = w0 + (px & 15);
    uint4* dst = (uint4*)w11T + (((b*HP + h+1)*HP) + (w+1))*8;
    const uint4* srcT = (const uint4*)&lds[px*72];
    #pragma unroll
    for (int k = 0; k < 8; ++k) dst[k] = srcT[k];
  }
  if (tid < 64){
    float* statsF = (float*)&lds[20000];
    poolP[(b*128 + tile)*64 + tid] = statsF[tid] + statsF[64 + tid];
  }
}

// ---------------- k2: pooled mean + w22 GEMV ----------------
__global__ void k2a_pool(const float* __restrict__ poolP, float* pooled){
  int t = threadIdx.x;                       // 256
  int b = t >> 6, c = t & 63;
  float s = 0.f;
  for (int tile = 0; tile < 128; ++tile) s += poolP[(b*128 + tile)*64 + c];
  pooled[t] = s * (1.f/16384.f);
}

__global__ void k2b_w22(const float* __restrict__ pooled, const float* __restrict__ W22,
                        const float* __restrict__ b22, float* __restrict__ w22){
  __shared__ float pl[64];
  int b = blockIdx.x >> 4, og = blockIdx.x & 15;
  if (threadIdx.x < 64) pl[threadIdx.x] = pooled[b*64 + threadIdx.x];
  __syncthreads();
  int o = og*256 + threadIdx.x;
  float acc = b22[o];
  #pragma unroll 4
  for (int c = 0; c < 64; ++c) acc += pl[c]*W22[o*64 + c];
  w22[b*4096 + o] = acc;
}

// ---------------- k3: fused conv12 + local_conv + BN1 stats ----------------
// per tap t: y = A12[t] @ im2col(w11) (K=576), then oacc += inpatch_t * (y + b12)
__global__ __launch_bounds__(256) void k3_fused(
    const bfu* __restrict__ w11T, const bfu* __restrict__ catT,
    const bfu* __restrict__ A12, const float* __restrict__ b12,
    float* __restrict__ out1, float* __restrict__ st1){
  __shared__ bfu lds[27968];                 // w11 tile [0,12960), inp tile [12960,25920), stats after
  int tid = threadIdx.x;
  int b = blockIdx.y, tile = blockIdx.x;
  int h0 = (tile >> 3)*8, w0 = (tile & 7)*16;

  const uint4* w11T4 = (const uint4*)w11T;
  const uint4* catT4 = (const uint4*)catT;
  for (int s = tid; s < 180*9; s += 256){
    int cell = s/9, sub = s%9;
    if (sub < 8){
      int th = cell/18, tw = cell%18;
      int pix = ((b*HP + h0+th)*HP) + (w0+tw);
      *(uint4*)&lds[cell*72 + sub*8]         = w11T4[pix*8 + sub];
      *(uint4*)&lds[12960 + cell*72 + sub*8] = catT4[pix*16 + sub];   // input = first 64 ch of cat
    }
  }
  __syncthreads();

  int wid = tid >> 6, l = tid & 63, lg = l >> 4, pc = l & 15;
  f32x4 oacc[4][2];
  #pragma unroll
  for (int i = 0; i < 4; ++i){ oacc[i][0] = f32x4{0.f,0.f,0.f,0.f}; oacc[i][1] = f32x4{0.f,0.f,0.f,0.f}; }

  const uint4* A4 = (const uint4*)A12;
  #pragma unroll 1
  for (int t = 0; t < 9; ++t){
    f32x4 y[4][2];
    #pragma unroll
    for (int i = 0; i < 4; ++i){ y[i][0] = f32x4{0.f,0.f,0.f,0.f}; y[i][1] = f32x4{0.f,0.f,0.f,0.f}; }
    #pragma unroll 1
    for (int tap2 = 0; tap2 < 9; ++tap2){
      int kh = tap2/3, kw = tap2%3;
      #pragma unroll
      for (int jc = 0; jc < 2; ++jc){
        bf16x8 a[4], bb[2];
        #pragma unroll
        for (int fm = 0; fm < 4; ++fm)
          a[fm] = __builtin_bit_cast(bf16x8, A4[(t*9 + tap2)*512 + (fm*16 + pc)*8 + jc*4 + lg]);
        #pragma unroll
        for (int fn = 0; fn < 2; ++fn){
          int cell = (wid*2 + fn + kh)*18 + (pc + kw);
          bb[fn] = ldsfrag(&lds[cell*72 + jc*32 + lg*8]);
        }
        #pragma unroll
        for (int fm = 0; fm < 4; ++fm)
          #pragma unroll
          for (int fn = 0; fn < 2; ++fn)
            y[fm][fn] = mfma16(a[fm], bb[fn], y[fm][fn]);
      }
    }
    int dh = t/3, dw = t%3;
    #pragma unroll
    for (int fm = 0; fm < 4; ++fm)
      #pragma unroll
      for (int r = 0; r < 4; ++r){
        int c = fm*16 + lg*4 + r;
        float bias = b12[c*9 + t];
        #pragma unroll
        for (int fn = 0; fn < 2; ++fn){
          int pr = wid*2 + fn;
          int cell = (pr + dh)*18 + (pc + dw);
          float inv = bf2f(lds[12960 + cell*72 + c]);
          oacc[fm][fn][r] += inv * (y[fm][fn][r] + bias);
        }
      }
  }

  float* wp = (float*)&lds[25920];
  #pragma unroll
  for (int fm = 0; fm < 4; ++fm)
    #pragma unroll
    for (int r = 0; r < 4; ++r){
      int c = fm*16 + lg*4 + r;
      float s = 0.f, ss = 0.f;
      #pragma unroll
      for (int fn = 0; fn < 2; ++fn){
        int pr = wid*2 + fn;
        float v = oacc[fm][fn][r];
        out1[((b*64 + c)*128 + h0 + pr)*128 + (w0 + pc)] = v;
        s += v; ss += v*v;
      }
      s += __shfl_xor(s,1); s += __shfl_xor(s,2); s += __shfl_xor(s,4); s += __shfl_xor(s,8);
      ss += __shfl_xor(ss,1); ss += __shfl_xor(ss,2); ss += __shfl_xor(ss,4); ss += __shfl_xor(ss,8);
      if (pc == 0){ wp[(wid*64 + c)*2] = s; wp[(wid*64 + c)*2 + 1] = ss; }
    }
  __syncthreads();
  if (tid < 64){
    float s = 0.f, ss = 0.f;
    #pragma unroll
    for (int w = 0; w < 4; ++w){ s += wp[(w*64 + tid)*2]; ss += wp[(w*64 + tid)*2 + 1]; }
    int blin = b*128 + tile;
    st1[(blin*64 + tid)*2] = s; st1[(blin*64 + tid)*2 + 1] = ss;
  }
}

// ---------------- BN stat reduce (generic) ----------------
__global__ void k_bnstat(const float* __restrict__ st, int nblk, float n,
                         const float* __restrict__ g, const float* __restrict__ bb, float* bn){
  int c = threadIdx.x;
  if (c >= 64) return;
  float s = 0.f, ss = 0.f;
  for (int k = 0; k < nblk; ++k){ s += st[(k*64 + c)*2]; ss += st[(k*64 + c)*2 + 1]; }
  float mean = s/n, var = ss/n - mean*mean;
  float a = g[c]*rsqrtf(var + EPSV);
  bn[c*2] = a; bn[c*2 + 1] = bb[c] - mean*a;
}

// ---------------- k4: einsum (w22 @ relu(bn1(out1))) + BN2 stats ----------------
__global__ __launch_bounds__(256) void k4_einsum(
    const float* __restrict__ out1, const float* __restrict__ w22,
    const float* __restrict__ bn1, float* __restrict__ out2, float* __restrict__ st2){
  __shared__ float w22s[4096];
  __shared__ float a1[64], be1[64];
  __shared__ float wp[512];
  int tid = threadIdx.x;
  int b = blockIdx.y, chunk = blockIdx.x;
  for (int k = tid; k < 4096; k += 256){
    int i = k >> 6, j = k & 63;
    w22s[j*64 + i] = w22[b*4096 + k];        // transpose: [j][i]
  }
  if (tid < 64){ a1[tid] = bn1[tid*2]; be1[tid] = bn1[tid*2 + 1]; }
  __syncthreads();

  int p = chunk*256 + tid;
  float acc[64];
  #pragma unroll
  for (int i = 0; i < 64; ++i) acc[i] = 0.f;
  #pragma unroll 2
  for (int j = 0; j < 64; ++j){
    float x = out1[(b*64 + j)*HW + p];
    x = a1[j]*x + be1[j];
    x = x > 0.f ? x : 0.f;
    const float4* wr = (const float4*)&w22s[j*64];
    #pragma unroll
    for (int i4 = 0; i4 < 16; ++i4){
      float4 w = wr[i4];
      acc[i4*4+0] += x*w.x; acc[i4*4+1] += x*w.y; acc[i4*4+2] += x*w.z; acc[i4*4+3] += x*w.w;
    }
  }
  int wid = tid >> 6;
  #pragma unroll
  for (int i = 0; i < 64; ++i){
    float v = acc[i];
    out2[(b*64 + i)*HW + p] = v;
    float s = v, ss = v*v;
    #pragma unroll
    for (int m = 1; m < 64; m <<= 1){ s += __shfl_xor(s, m); ss += __shfl_xor(ss, m); }
    if ((tid & 63) == 0){ wp[(wid*64 + i)*2] = s; wp[(wid*64 + i)*2 + 1] = ss; }
  }
  __syncthreads();
  if (tid < 64){
    float s = 0.f, ss = 0.f;
    #pragma unroll
    for (int w = 0; w < 4; ++w){ s += wp[(w*64 + tid)*2]; ss += wp[(w*64 + tid)*2 + 1]; }
    int blin = b*64 + chunk;
    st2[(blin*64 + tid)*2] = s; st2[(blin*64 + tid)*2 + 1] = ss;
  }
}

// ---------------- k4c: out3T = relu(bn2(out2)) as NHWC bf16 padded ----------------
__global__ void k4c_out3(const float* __restrict__ out2, const float* __restrict__ bn2, bfu* out3T){
  const int total = 4*HW*64;
  for (int i = blockIdx.x*256 + threadIdx.x; i < total; i += gridDim.x*256){
    int c = i & 63; int w = (i >> 6) & 127; int h = (i >> 13) & 127; int b = i >> 20;
    float x = out2[((b*64 + c) << 14) + (h << 7) + w];
    x = bn2[c*2]*x + bn2[c*2 + 1];
    x = x > 0.f ? x : 0.f;
    out3T[((b*HP + h+1)*HP + (w+1))*64 + c] = f2bf(x);
  }
}

// ---------------- k5: conv3 (implicit GEMM M=64,K=576) + BN3 stats ----------------
__global__ __launch_bounds__(256) void k5_conv3(
    const bfu* __restrict__ out3T, const bfu* __restrict__ A3,
    float* __restrict__ outc, float* __restrict__ st3){
  __shared__ bfu lds[25376];                 // 324 cells * 72 u16 + stats
  int tid = threadIdx.x;
  int b = blockIdx.y, tile = blockIdx.x;     // 0..63
  int h0 = (tile >> 3)*16, w0 = (tile & 7)*16;
  const uint4* src4 = (const uint4*)out3T;
  for (int s = tid; s < 324*9; s += 256){
    int cell = s/9, sub = s%9;
    if (sub < 8){
      int th = cell/18, tw = cell%18;
      *(uint4*)&lds[cell*72 + sub*8] = src4[(((b*HP + h0+th)*HP) + (w0+tw))*8 + sub];
    }
  }
  __syncthreads();

  int wid = tid >> 6, l = tid & 63, lg = l >> 4, pc = l & 15;
  f32x4 acc[4][4];
  #pragma unroll
  for (int i = 0; i < 4; ++i)
    #pragma unroll
    for (int j = 0; j < 4; ++j) acc[i][j] = f32x4{0.f,0.f,0.f,0.f};
  const uint4* A4 = (const uint4*)A3;
  #pragma unroll 1
  for (int tap2 = 0; tap2 < 9; ++tap2){
    int kh = tap2/3, kw = tap2%3;
    #pragma unroll
    for (int jc = 0; jc < 2; ++jc){
      bf16x8 a[4], bb[4];
      #pragma unroll
      for (int fm = 0; fm < 4; ++fm)
        a[fm] = __builtin_bit_cast(bf16x8, A4[tap2*512 + (fm*16 + pc)*8 + jc*4 + lg]);
      #pragma unroll
      for (int fn = 0; fn < 4; ++fn){
        int cell = (wid*4 + fn + kh)*18 + (pc + kw);
        bb[fn] = ldsfrag(&lds[cell*72 + jc*32 + lg*8]);
      }
      #pragma unroll
      for (int fm = 0; fm < 4; ++fm)
        #pragma unroll
        for (int fn = 0; fn < 4; ++fn)
          acc[fm][fn] = mfma16(a[fm], bb[fn], acc[fm][fn]);
    }
  }
  float* wp = (float*)&lds[23328];
  #pragma unroll
  for (int fm = 0; fm < 4; ++fm)
    #pragma unroll
    for (int r = 0; r < 4; ++r){
      int c = fm*16 + lg*4 + r;
      float s = 0.f, ss = 0.f;
      #pragma unroll
      for (int fn = 0; fn < 4; ++fn){
        int pr = wid*4 + fn;
        float v = acc[fm][fn][r];
        outc[((b*64 + c)*128 + h0 + pr)*128 + (w0 + pc)] = v;
        s += v; ss += v*v;
      }
      s += __shfl_xor(s,1); s += __shfl_xor(s,2); s += __shfl_xor(s,4); s += __shfl_xor(s,8);
      ss += __shfl_xor(ss,1); ss += __shfl_xor(ss,2); ss += __shfl_xor(ss,4); ss += __shfl_xor(ss,8);
      if (pc == 0){ wp[(wid*64 + c)*2] = s; wp[(wid*64 + c)*2 + 1] = ss; }
    }
  __syncthreads();
  if (tid < 64){
    float s = 0.f, ss = 0.f;
    #pragma unroll
    for (int w = 0; w < 4; ++w){ s += wp[(w*64 + tid)*2]; ss += wp[(w*64 + tid)*2 + 1]; }
    int blin = b*64 + tile;
    st3[(blin*64 + tid)*2] = s; st3[(blin*64 + tid)*2 + 1] = ss;
  }
}

// ---------------- k6: final relu(bn3(conv3_pre)) in place on d_out ----------------
__global__ void k6_final(float* __restrict__ out, const float* __restrict__ bn3){
  const int total = 4*64*HW;
  for (int i = blockIdx.x*256 + threadIdx.x; i < total; i += gridDim.x*256){
    int c = (i >> 14) & 63;
    float x = out[i];
    x = bn3[c*2]*x + bn3[c*2 + 1];
    out[i] = x > 0.f ? x : 0.f;
  }
}

extern "C" void kernel_launch(void* const* d_in, const int* in_sizes, int n_in,
                              void* d_out, int out_size, void* d_ws, size_t ws_size,
                              hipStream_t stream){
  const float* inp  = (const float*)d_in[0];
  const float* wgt  = (const float*)d_in[1];
  const float* w11w = (const float*)d_in[2];
  const float* b11  = (const float*)d_in[3];
  const float* w12w = (const float*)d_in[4];
  const float* b12  = (const float*)d_in[5];
  const float* w21w = (const float*)d_in[6];
  const float* b21  = (const float*)d_in[7];
  const float* W22  = (const float*)d_in[8];
  const float* b22  = (const float*)d_in[9];
  const float* lg   = (const float*)d_in[10];
  const float* lb   = (const float*)d_in[11];
  const float* brg  = (const float*)d_in[12];
  const float* brb  = (const float*)d_in[13];
  const float* w3w  = (const float*)d_in[14];
  const float* c3g  = (const float*)d_in[15];
  const float* c3b  = (const float*)d_in[16];

  if (ws_size < 53200000) return;  // layout requires ~50.7 MB

  char* ws = (char*)d_ws;
  bfu*   catT  = (bfu*)(ws);                     // 17,305,600
  bfu*   w11T  = (bfu*)(ws + 17305600);          //  8,652,800
  bfu*   out3T = (bfu*)(ws + 25958400);          //  8,652,800
  bfu*   A11   = (bfu*)(ws + 34611200);          //    294,912
  bfu*   A12   = (bfu*)(ws + 34906112);          //    663,552
  bfu*   A3    = (bfu*)(ws + 35569664);          //     73,728
  float* out1  = (float*)(ws + 35643392);        // 16,777,216
  float* poolP = (float*)(ws + 52420608);        //    131,072
  float* pooled= (float*)(ws + 52551680);        //      1,024
  float* w22   = (float*)(ws + 52552704);        //     65,536
  float* st1   = (float*)(ws + 52618240);        //    262,144
  float* bn1   = (float*)(ws + 52880384);        //        512
  float* st2   = (float*)(ws + 52880896);        //    131,072
  float* bn2   = (float*)(ws + 53011968);        //        512
  float* st3   = (float*)(ws + 53012480);        //    131,072
  float* bn3   = (float*)(ws + 53143552);        //        512
  float* outF  = (float*)d_out;                  // reused: out2_pre, then conv3_pre, then out4

  k_zero    <<<dim3(1024), dim3(256), 0, stream>>>((uint4*)w11T, 17305600/16); // w11T + out3T borders
  k_prep_w  <<<dim3(512),  dim3(256), 0, stream>>>(w11w, w21w, w12w, w3w, A11, A12, A3);
  k_prep_cat<<<dim3(2048), dim3(256), 0, stream>>>(inp, wgt, catT);
  k1_conv   <<<dim3(128,4),dim3(256), 0, stream>>>(catT, A11, b11, b21, w11T, poolP);
  k2a_pool  <<<dim3(1),    dim3(256), 0, stream>>>(poolP, pooled);
  k2b_w22   <<<dim3(64),   dim3(256), 0, stream>>>(pooled, W22, b22, w22);
  k3_fused  <<<dim3(128,4),dim3(256), 0, stream>>>(w11T, catT, A12, b12, out1, st1);
  k_bnstat  <<<dim3(1),    dim3(64),  0, stream>>>(st1, 512, 65536.f, lg, lb, bn1);
  k4_einsum <<<dim3(64,4), dim3(256), 0, stream>>>(out1, w22, bn1, outF, st2);
  k_bnstat  <<<dim3(1),    dim3(64),  0, stream>>>(st2, 256, 65536.f, brg, brb, bn2);
  k4c_out3  <<<dim3(2048), dim3(256), 0, stream>>>(outF, bn2, out3T);
  k5_conv3  <<<dim3(64,4), dim3(256), 0, stream>>>(out3T, A3, outF, st3);
  k_bnstat  <<<dim3(1),    dim3(64),  0, stream>>>(st3, 256, 65536.f, c3g, c3b, bn3);
  k6_final  <<<dim3(2048), dim3(256), 0, stream>>>(outF, bn3);
}

// Round 2
// 476.249 us; speedup vs baseline: 1.3562x; 1.3562x over previous
//
#include <hip/hip_runtime.h>

#define EPSV 1e-5f
#define HP 130            // padded H/W
#define HW 16384          // 128*128

typedef unsigned int u32;
typedef unsigned short bfu;                                    // bf16 storage
typedef __bf16 bf16x8 __attribute__((ext_vector_type(8)));
typedef float  f32x4  __attribute__((ext_vector_type(4)));

__device__ __forceinline__ bfu f2bf(float f){
  u32 u = __builtin_bit_cast(u32, f);
  return (bfu)((u + 0x7FFFu + ((u >> 16) & 1u)) >> 16);        // RNE
}
__device__ __forceinline__ float bf2f(bfu h){
  return __builtin_bit_cast(float, ((u32)h) << 16);
}
__device__ __forceinline__ f32x4 mfma16(bf16x8 a, bf16x8 b, f32x4 c){
  return __builtin_amdgcn_mfma_f32_16x16x32_bf16(a, b, c, 0, 0, 0);
}
__device__ __forceinline__ bf16x8 ldsfrag(const bfu* p){
  return __builtin_bit_cast(bf16x8, *(const uint4*)p);
}

// ---------------- prep kernels ----------------

// zero catT + w11T + out3T (contiguous 34,611,200 B)
__global__ void k_zero(uint4* p, int n4){
  uint4 z = {0,0,0,0};
  for (int i = blockIdx.x*256 + threadIdx.x; i < n4; i += gridDim.x*256) p[i] = z;
}

// weight reorders -> bf16.  A11[tap][och128][cin128]; A12[t][tap2][c64][j64]; A3[tap2][oc64][j64]
__global__ void k_prep_w(const float* __restrict__ w11w, const float* __restrict__ w21w,
                         const float* __restrict__ w12w, const float* __restrict__ w3w,
                         bfu* A11, bfu* A12, bfu* A3){
  const int total = 147456 + 331776 + 36864;
  for (int i = blockIdx.x*256 + threadIdx.x; i < total; i += gridDim.x*256){
    float v; bfu* dst;
    if (i < 147456){
      int tap = i >> 14, och = (i >> 7) & 127, cin = i & 127;
      v = (och < 64) ? w11w[(och*128 + cin)*9 + tap] : w21w[((och-64)*128 + cin)*9 + tap];
      dst = A11 + i;
    } else if (i < 147456 + 331776){
      int i2 = i - 147456;
      int g = i2 >> 12, t = g/9, tap2 = g%9;
      int c = (i2 >> 6) & 63, j = i2 & 63;
      v = w12w[((c*9 + t)*64 + j)*9 + tap2];
      dst = A12 + i2;
    } else {
      int i3 = i - (147456 + 331776);
      int tap2 = i3 >> 12, oc = (i3 >> 6) & 63, j = i3 & 63;
      v = w3w[(oc*64 + j)*9 + tap2];
      dst = A3 + i3;
    }
    *dst = f2bf(v);
  }
}

// catT interior: NHWC bf16 [b][130][130][128ch]; coalesced read via LDS transpose
__global__ void k_prep_cat(const float* __restrict__ inp, const float* __restrict__ wgt, bfu* catT){
  __shared__ bfu lds[128*136];               // [w][ch], 272B row (17 x 16B)
  int b = blockIdx.y, h = blockIdx.x;        // grid (128,4)
  int t = threadIdx.x;
  int w = t & 127, c0 = t >> 7;
  #pragma unroll 1
  for (int c = c0; c < 128; c += 2){
    const float* src = (c < 64) ? inp + ((b*64 + c)*128 + h)*128
                                : wgt + ((b*64 + (c-64))*128 + h)*128;
    lds[w*136 + c] = f2bf(src[w]);
  }
  __syncthreads();
  uint4* dst = (uint4*)catT;
  #pragma unroll
  for (int k = 0; k < 8; ++k){
    int idx = k*256 + t;                     // 0..2047
    int pix = idx >> 4, sub = idx & 15;
    uint4 v = *(const uint4*)&lds[pix*136 + sub*8];
    dst[(((b*HP + h+1)*HP) + (pix+1))*16 + sub] = v;
  }
}

// ---------------- k1: conv11 + conv21 (implicit GEMM, M=128, K=9*128) ----------------
__global__ __launch_bounds__(256) void k1_conv(
    const bfu* __restrict__ catT, const bfu* __restrict__ A11,
    const float* __restrict__ b11, const float* __restrict__ b21,
    bfu* __restrict__ w11T, float* __restrict__ poolP){
  __shared__ bfu lds[24480];                 // 180 cells * 136 u16
  int tid = threadIdx.x;
  int b = blockIdx.y, tile = blockIdx.x;     // 0..127
  int h0 = (tile >> 3)*8, w0 = (tile & 7)*16;

  const uint4* catT4 = (const uint4*)catT;
  for (int s = tid; s < 180*17; s += 256){
    int cell = s/17, sub = s%17;
    if (sub < 16){
      int th = cell/18, tw = cell%18;
      uint4 v = catT4[(((b*HP + h0+th)*HP) + (w0+tw))*16 + sub];
      *(uint4*)&lds[cell*136 + sub*8] = v;
    }
  }
  __syncthreads();

  int wid = tid >> 6, l = tid & 63, lg = l >> 4, pc = l & 15;
  int wm = wid >> 1, wn = wid & 1;
  f32x4 acc[4][4];
  #pragma unroll
  for (int i = 0; i < 4; ++i)
    #pragma unroll
    for (int j = 0; j < 4; ++j) acc[i][j] = f32x4{0.f,0.f,0.f,0.f};

  const uint4* A4 = (const uint4*)A11;
  #pragma unroll 1
  for (int tap = 0; tap < 9; ++tap){
    int kh = tap/3, kw = tap%3;
    #pragma unroll
    for (int jc = 0; jc < 4; ++jc){
      bf16x8 a[4], bb[4];
      #pragma unroll
      for (int fm = 0; fm < 4; ++fm){
        int row = wm*64 + fm*16 + pc;
        a[fm] = __builtin_bit_cast(bf16x8, A4[(tap*128 + row)*16 + jc*4 + lg]);
      }
      #pragma unroll
      for (int fn = 0; fn < 4; ++fn){
        int cell = (wn*4 + fn + kh)*18 + (pc + kw);
        bb[fn] = ldsfrag(&lds[cell*136 + jc*32 + lg*8]);
      }
      #pragma unroll
      for (int fm = 0; fm < 4; ++fm)
        #pragma unroll
        for (int fn = 0; fn < 4; ++fn)
          acc[fm][fn] = mfma16(a[fm], bb[fn], acc[fm][fn]);
    }
  }
  __syncthreads();

  if (wm == 0){                              // w11 path
    #pragma unroll
    for (int fm = 0; fm < 4; ++fm)
      #pragma unroll
      for (int r = 0; r < 4; ++r){
        int och = fm*16 + lg*4 + r;
        float bias = b11[och];
        #pragma unroll
        for (int fn = 0; fn < 4; ++fn){
          float v = acc[fm][fn][r] + bias;
          v = v > 0.f ? v : 0.f;
          int px = wn*64 + fn*16 + pc;
          lds[px*72 + och] = f2bf(v);
        }
      }
  } else {                                   // w21 path: pooled partials
    float* statsF = (float*)&lds[20000];
    #pragma unroll
    for (int fm = 0; fm < 4; ++fm)
      #pragma unroll
      for (int r = 0; r < 4; ++r){
        int cw = fm*16 + lg*4 + r;
        float bias = b21[cw];
        float s = 0.f;
        #pragma unroll
        for (int fn = 0; fn < 4; ++fn){
          float v = acc[fm][fn][r] + bias;
          s += (v > 0.f ? v : 0.f);
        }
        s += __shfl_xor(s,1); s += __shfl_xor(s,2); s += __shfl_xor(s,4); s += __shfl_xor(s,8);
        if (pc == 0) statsF[wn*64 + cw] = s;
      }
  }
  __syncthreads();

  if (wid < 2){
    int px = tid;
    int h = h0 + (px >> 4), w = w0 + (px & 15);
    uint4* dst = (uint4*)w11T + (((b*HP + h+1)*HP) + (w+1))*8;
    const uint4* srcT = (const uint4*)&lds[px*72];
    #pragma unroll
    for (int k = 0; k < 8; ++k) dst[k] = srcT[k];
  }
  if (tid < 64){
    float* statsF = (float*)&lds[20000];
    poolP[(b*128 + tile)*64 + tid] = statsF[tid] + statsF[64 + tid];
  }
}

// ---------------- k2: pooled mean + w22 GEMV ----------------
__global__ void k2a_pool(const float* __restrict__ poolP, float* pooled){
  int t = threadIdx.x;
  int b = t >> 6, c = t & 63;
  float s = 0.f;
  for (int tile = 0; tile < 128; ++tile) s += poolP[(b*128 + tile)*64 + c];
  pooled[t] = s * (1.f/16384.f);
}

__global__ void k2b_w22(const float* __restrict__ pooled, const float* __restrict__ W22,
                        const float* __restrict__ b22, float* __restrict__ w22){
  __shared__ float pl[64];
  int b = blockIdx.x >> 4, og = blockIdx.x & 15;
  if (threadIdx.x < 64) pl[threadIdx.x] = pooled[b*64 + threadIdx.x];
  __syncthreads();
  int o = og*256 + threadIdx.x;
  float acc = b22[o];
  #pragma unroll 4
  for (int c = 0; c < 64; ++c) acc += pl[c]*W22[o*64 + c];
  w22[b*4096 + o] = acc;
}

// ---------------- k3: fused conv12 + local_conv + BN1 stats (rewritten) ----------------
// 16x16 pixel tile, 4 waves, wave tile M=64 x N=64 (fm=4, fn=4).
// A12 slice (t,tap2) = 64x64 double-buffered in LDS in fragment-linear layout.
// w11 tile in LDS, 128B/cell, XOR-swizzled. inv read from catT (L2).
__global__ __launch_bounds__(256) void k3_fused(
    const bfu* __restrict__ w11T, const bfu* __restrict__ catT,
    const bfu* __restrict__ A12, const float* __restrict__ b12,
    float* __restrict__ out1, float* __restrict__ st1){
  __shared__ bfu ldsW[324*64];               // 41,472 B, swizzled
  __shared__ bfu ldsA[2*4096];               // 16,384 B, frag-linear
  __shared__ float b12f[576];
  __shared__ float wp[4*64*2];
  int tid = threadIdx.x;
  int b = blockIdx.y, tile = blockIdx.x;     // 0..63
  int h0 = (tile >> 3)*16, w0 = (tile & 7)*16;

  // stage w11 tile (18x18 cells x 64ch), swizzle slot = sub ^ (cell&7)
  const uint4* w11T4 = (const uint4*)w11T;
  for (int s = tid; s < 324*8; s += 256){
    int cell = s >> 3, sub = s & 7;
    int th = cell/18, tw = cell - th*18;
    uint4 v = w11T4[(((b*HP + h0+th)*HP) + (w0+tw))*8 + sub];
    *(uint4*)&ldsW[cell*64 + ((sub*8) ^ ((cell&7)<<3))] = v;
  }
  for (int i = tid; i < 576; i += 256) b12f[i] = b12[i];

  // A staging constants (thread -> frag-linear dest)
  const uint4* A4 = (const uint4*)A12;
  int fmT = tid >> 6, rT = (tid >> 2) & 15;
  int jcT = (tid & 3) >> 1, qk0 = (tid & 1)*2;   // ((tid&3)*2)&3 == (tid&1)*2
  int dst0 = ((fmT*2 + jcT)*4 + qk0)*16 + rT;    // uint4 index; dst1 = dst0+16
  uint4* ldsA4 = (uint4*)ldsA;

  // prologue: slice 0
  uint4 g0 = A4[tid*2], g1 = A4[tid*2 + 1];
  ldsA4[dst0] = g0; ldsA4[dst0 + 16] = g1;

  int wid = tid >> 6, l = tid & 63, lg = l >> 4, pc = l & 15;
  int w4 = wid*4;
  f32x4 oacc[4][4];
  #pragma unroll
  for (int i = 0; i < 4; ++i)
    #pragma unroll
    for (int j = 0; j < 4; ++j) oacc[i][j] = f32x4{0.f,0.f,0.f,0.f};

  int cur = 0;
  #pragma unroll 1
  for (int tt = 0; tt < 9; ++tt){
    f32x4 y[4][4];
    #pragma unroll
    for (int i = 0; i < 4; ++i)
      #pragma unroll
      for (int j = 0; j < 4; ++j) y[i][j] = f32x4{0.f,0.f,0.f,0.f};

    #pragma unroll 1
    for (int tap2 = 0; tap2 < 9; ++tap2){
      int s = tt*9 + tap2;
      if (s < 80){ g0 = A4[(s+1)*512 + tid*2]; g1 = A4[(s+1)*512 + tid*2 + 1]; }
      __syncthreads();                       // ldsA[cur] ready
      int kh = tap2/3, kw = tap2 - kh*3;
      #pragma unroll
      for (int jc = 0; jc < 2; ++jc){
        bf16x8 a[4], bb[4];
        #pragma unroll
        for (int fm = 0; fm < 4; ++fm)
          a[fm] = __builtin_bit_cast(bf16x8, ldsA4[cur*512 + (fm*2 + jc)*64 + l]);
        #pragma unroll
        for (int fn = 0; fn < 4; ++fn){
          int cell = (w4 + fn + kh)*18 + (pc + kw);
          bb[fn] = ldsfrag(&ldsW[cell*64 + ((jc*32 + lg*8) ^ ((cell&7)<<3))]);
        }
        #pragma unroll
        for (int fm = 0; fm < 4; ++fm)
          #pragma unroll
          for (int fn = 0; fn < 4; ++fn)
            y[fm][fn] = mfma16(a[fm], bb[fn], y[fm][fn]);
      }
      if (s < 80){ ldsA4[(cur^1)*512 + dst0] = g0; ldsA4[(cur^1)*512 + dst0 + 16] = g1; }
      __syncthreads();                       // next buffer written
      cur ^= 1;
    }

    // epilogue for tap tt: oacc += inp[c, p+delta] * (y + bias)
    int dh = tt/3, dw = tt - dh*3;
    #pragma unroll
    for (int fn = 0; fn < 4; ++fn){
      const bfu* base = catT + (((b*HP + h0 + w4 + fn + dh)*HP) + (w0 + pc + dw))*128 + lg*4;
      #pragma unroll
      for (int fm = 0; fm < 4; ++fm)
        #pragma unroll
        for (int r = 0; r < 4; ++r){
          int c = fm*16 + lg*4 + r;
          float inv = bf2f(base[fm*16 + r]);
          oacc[fm][fn][r] += inv * (y[fm][fn][r] + b12f[c*9 + tt]);
        }
    }
  }

  // write out1 + per-block BN stats
  #pragma unroll
  for (int fm = 0; fm < 4; ++fm)
    #pragma unroll
    for (int r = 0; r < 4; ++r){
      int c = fm*16 + lg*4 + r;
      float s = 0.f, ss = 0.f;
      #pragma unroll
      for (int fn = 0; fn < 4; ++fn){
        float v = oacc[fm][fn][r];
        out1[((b*64 + c)*128 + h0 + w4 + fn)*128 + (w0 + pc)] = v;
        s += v; ss += v*v;
      }
      s += __shfl_xor(s,1); s += __shfl_xor(s,2); s += __shfl_xor(s,4); s += __shfl_xor(s,8);
      ss += __shfl_xor(ss,1); ss += __shfl_xor(ss,2); ss += __shfl_xor(ss,4); ss += __shfl_xor(ss,8);
      if (pc == 0){ wp[(wid*64 + c)*2] = s; wp[(wid*64 + c)*2 + 1] = ss; }
    }
  __syncthreads();
  if (tid < 64){
    float s = 0.f, ss = 0.f;
    #pragma unroll
    for (int w = 0; w < 4; ++w){ s += wp[(w*64 + tid)*2]; ss += wp[(w*64 + tid)*2 + 1]; }
    int blin = b*64 + tile;
    st1[(blin*64 + tid)*2] = s; st1[(blin*64 + tid)*2 + 1] = ss;
  }
}

// ---------------- BN stat reduce (generic) ----------------
__global__ void k_bnstat(const float* __restrict__ st, int nblk, float n,
                         const float* __restrict__ g, const float* __restrict__ bb, float* bn){
  int c = threadIdx.x;
  if (c >= 64) return;
  float s = 0.f, ss = 0.f;
  for (int k = 0; k < nblk; ++k){ s += st[(k*64 + c)*2]; ss += st[(k*64 + c)*2 + 1]; }
  float mean = s/n, var = ss/n - mean*mean;
  float a = g[c]*rsqrtf(var + EPSV);
  bn[c*2] = a; bn[c*2 + 1] = bb[c] - mean*a;
}

// ---------------- k4: einsum + BN2 stats ----------------
__global__ __launch_bounds__(256) void k4_einsum(
    const float* __restrict__ out1, const float* __restrict__ w22,
    const float* __restrict__ bn1, float* __restrict__ out2, float* __restrict__ st2){
  __shared__ float w22s[4096];
  __shared__ float a1[64], be1[64];
  __shared__ float wp[512];
  int tid = threadIdx.x;
  int b = blockIdx.y, chunk = blockIdx.x;
  for (int k = tid; k < 4096; k += 256){
    int i = k >> 6, j = k & 63;
    w22s[j*64 + i] = w22[b*4096 + k];
  }
  if (tid < 64){ a1[tid] = bn1[tid*2]; be1[tid] = bn1[tid*2 + 1]; }
  __syncthreads();

  int p = chunk*256 + tid;
  float acc[64];
  #pragma unroll
  for (int i = 0; i < 64; ++i) acc[i] = 0.f;
  #pragma unroll 2
  for (int j = 0; j < 64; ++j){
    float x = out1[(b*64 + j)*HW + p];
    x = a1[j]*x + be1[j];
    x = x > 0.f ? x : 0.f;
    const float4* wr = (const float4*)&w22s[j*64];
    #pragma unroll
    for (int i4 = 0; i4 < 16; ++i4){
      float4 w = wr[i4];
      acc[i4*4+0] += x*w.x; acc[i4*4+1] += x*w.y; acc[i4*4+2] += x*w.z; acc[i4*4+3] += x*w.w;
    }
  }
  int wid = tid >> 6;
  #pragma unroll
  for (int i = 0; i < 64; ++i){
    float v = acc[i];
    out2[(b*64 + i)*HW + p] = v;
    float s = v, ss = v*v;
    #pragma unroll
    for (int m = 1; m < 64; m <<= 1){ s += __shfl_xor(s, m); ss += __shfl_xor(ss, m); }
    if ((tid & 63) == 0){ wp[(wid*64 + i)*2] = s; wp[(wid*64 + i)*2 + 1] = ss; }
  }
  __syncthreads();
  if (tid < 64){
    float s = 0.f, ss = 0.f;
    #pragma unroll
    for (int w = 0; w < 4; ++w){ s += wp[(w*64 + tid)*2]; ss += wp[(w*64 + tid)*2 + 1]; }
    int blin = b*64 + chunk;
    st2[(blin*64 + tid)*2] = s; st2[(blin*64 + tid)*2 + 1] = ss;
  }
}

// ---------------- k4c: out3T = relu(bn2(out2)) NHWC bf16 padded ----------------
__global__ void k4c_out3(const float* __restrict__ out2, const float* __restrict__ bn2, bfu* out3T){
  const int total = 4*HW*64;
  for (int i = blockIdx.x*256 + threadIdx.x; i < total; i += gridDim.x*256){
    int c = i & 63; int w = (i >> 6) & 127; int h = (i >> 13) & 127; int b = i >> 20;
    float x = out2[((b*64 + c) << 14) + (h << 7) + w];
    x = bn2[c*2]*x + bn2[c*2 + 1];
    x = x > 0.f ? x : 0.f;
    out3T[((b*HP + h+1)*HP + (w+1))*64 + c] = f2bf(x);
  }
}

// ---------------- k5: conv3 (implicit GEMM M=64,K=576) + BN3 stats ----------------
__global__ __launch_bounds__(256) void k5_conv3(
    const bfu* __restrict__ out3T, const bfu* __restrict__ A3,
    float* __restrict__ outc, float* __restrict__ st3){
  __shared__ bfu lds[25376];
  int tid = threadIdx.x;
  int b = blockIdx.y, tile = blockIdx.x;     // 0..63
  int h0 = (tile >> 3)*16, w0 = (tile & 7)*16;
  const uint4* src4 = (const uint4*)out3T;
  for (int s = tid; s < 324*9; s += 256){
    int cell = s/9, sub = s%9;
    if (sub < 8){
      int th = cell/18, tw = cell%18;
      *(uint4*)&lds[cell*72 + sub*8] = src4[(((b*HP + h0+th)*HP) + (w0+tw))*8 + sub];
    }
  }
  __syncthreads();

  int wid = tid >> 6, l = tid & 63, lg = l >> 4, pc = l & 15;
  f32x4 acc[4][4];
  #pragma unroll
  for (int i = 0; i < 4; ++i)
    #pragma unroll
    for (int j = 0; j < 4; ++j) acc[i][j] = f32x4{0.f,0.f,0.f,0.f};
  const uint4* A4 = (const uint4*)A3;
  #pragma unroll 1
  for (int tap2 = 0; tap2 < 9; ++tap2){
    int kh = tap2/3, kw = tap2%3;
    #pragma unroll
    for (int jc = 0; jc < 2; ++jc){
      bf16x8 a[4], bb[4];
      #pragma unroll
      for (int fm = 0; fm < 4; ++fm)
        a[fm] = __builtin_bit_cast(bf16x8, A4[tap2*512 + (fm*16 + pc)*8 + jc*4 + lg]);
      #pragma unroll
      for (int fn = 0; fn < 4; ++fn){
        int cell = (wid*4 + fn + kh)*18 + (pc + kw);
        bb[fn] = ldsfrag(&lds[cell*72 + jc*32 + lg*8]);
      }
      #pragma unroll
      for (int fm = 0; fm < 4; ++fm)
        #pragma unroll
        for (int fn = 0; fn < 4; ++fn)
          acc[fm][fn] = mfma16(a[fm], bb[fn], acc[fm][fn]);
    }
  }
  float* wp = (float*)&lds[23328];
  #pragma unroll
  for (int fm = 0; fm < 4; ++fm)
    #pragma unroll
    for (int r = 0; r < 4; ++r){
      int c = fm*16 + lg*4 + r;
      float s = 0.f, ss = 0.f;
      #pragma unroll
      for (int fn = 0; fn < 4; ++fn){
        int pr = wid*4 + fn;
        float v = acc[fm][fn][r];
        outc[((b*64 + c)*128 + h0 + pr)*128 + (w0 + pc)] = v;
        s += v; ss += v*v;
      }
      s += __shfl_xor(s,1); s += __shfl_xor(s,2); s += __shfl_xor(s,4); s += __shfl_xor(s,8);
      ss += __shfl_xor(ss,1); ss += __shfl_xor(ss,2); ss += __shfl_xor(ss,4); ss += __shfl_xor(ss,8);
      if (pc == 0){ wp[(wid*64 + c)*2] = s; wp[(wid*64 + c)*2 + 1] = ss; }
    }
  __syncthreads();
  if (tid < 64){
    float s = 0.f, ss = 0.f;
    #pragma unroll
    for (int w = 0; w < 4; ++w){ s += wp[(w*64 + tid)*2]; ss += wp[(w*64 + tid)*2 + 1]; }
    int blin = b*64 + tile;
    st3[(blin*64 + tid)*2] = s; st3[(blin*64 + tid)*2 + 1] = ss;
  }
}

// ---------------- k6: final relu(bn3(conv3_pre)) in place on d_out ----------------
__global__ void k6_final(float* __restrict__ out, const float* __restrict__ bn3){
  const int total = 4*64*HW;
  for (int i = blockIdx.x*256 + threadIdx.x; i < total; i += gridDim.x*256){
    int c = (i >> 14) & 63;
    float x = out[i];
    x = bn3[c*2]*x + bn3[c*2 + 1];
    out[i] = x > 0.f ? x : 0.f;
  }
}

extern "C" void kernel_launch(void* const* d_in, const int* in_sizes, int n_in,
                              void* d_out, int out_size, void* d_ws, size_t ws_size,
                              hipStream_t stream){
  const float* inp  = (const float*)d_in[0];
  const float* wgt  = (const float*)d_in[1];
  const float* w11w = (const float*)d_in[2];
  const float* b11  = (const float*)d_in[3];
  const float* w12w = (const float*)d_in[4];
  const float* b12  = (const float*)d_in[5];
  const float* w21w = (const float*)d_in[6];
  const float* b21  = (const float*)d_in[7];
  const float* W22  = (const float*)d_in[8];
  const float* b22  = (const float*)d_in[9];
  const float* lg   = (const float*)d_in[10];
  const float* lb   = (const float*)d_in[11];
  const float* brg  = (const float*)d_in[12];
  const float* brb  = (const float*)d_in[13];
  const float* w3w  = (const float*)d_in[14];
  const float* c3g  = (const float*)d_in[15];
  const float* c3b  = (const float*)d_in[16];

  if (ws_size < 53200000) return;

  char* ws = (char*)d_ws;
  bfu*   catT  = (bfu*)(ws);                     // 17,305,600
  bfu*   w11T  = (bfu*)(ws + 17305600);          //  8,652,800
  bfu*   out3T = (bfu*)(ws + 25958400);          //  8,652,800
  bfu*   A11   = (bfu*)(ws + 34611200);          //    294,912
  bfu*   A12   = (bfu*)(ws + 34906112);          //    663,552
  bfu*   A3    = (bfu*)(ws + 35569664);          //     73,728
  float* out1  = (float*)(ws + 35643392);        // 16,777,216
  float* poolP = (float*)(ws + 52420608);        //    131,072
  float* pooled= (float*)(ws + 52551680);        //      1,024
  float* w22   = (float*)(ws + 52552704);        //     65,536
  float* st1   = (float*)(ws + 52618240);        //    262,144
  float* bn1   = (float*)(ws + 52880384);        //        512
  float* st2   = (float*)(ws + 52880896);        //    131,072
  float* bn2   = (float*)(ws + 53011968);        //        512
  float* st3   = (float*)(ws + 53012480);        //    131,072
  float* bn3   = (float*)(ws + 53143552);        //        512
  float* outF  = (float*)d_out;

  k_zero    <<<dim3(1024), dim3(256), 0, stream>>>((uint4*)ws, 34611200/16); // catT+w11T+out3T
  k_prep_w  <<<dim3(512),  dim3(256), 0, stream>>>(w11w, w21w, w12w, w3w, A11, A12, A3);
  k_prep_cat<<<dim3(128,4),dim3(256), 0, stream>>>(inp, wgt, catT);
  k1_conv   <<<dim3(128,4),dim3(256), 0, stream>>>(catT, A11, b11, b21, w11T, poolP);
  k2a_pool  <<<dim3(1),    dim3(256), 0, stream>>>(poolP, pooled);
  k2b_w22   <<<dim3(64),   dim3(256), 0, stream>>>(pooled, W22, b22, w22);
  k3_fused  <<<dim3(64,4), dim3(256), 0, stream>>>(w11T, catT, A12, b12, out1, st1);
  k_bnstat  <<<dim3(1),    dim3(64),  0, stream>>>(st1, 256, 65536.f, lg, lb, bn1);
  k4_einsum <<<dim3(64,4), dim3(256), 0, stream>>>(out1, w22, bn1, outF, st2);
  k_bnstat  <<<dim3(1),    dim3(64),  0, stream>>>(st2, 256, 65536.f, brg, brb, bn2);
  k4c_out3  <<<dim3(2048), dim3(256), 0, stream>>>(outF, bn2, out3T);
  k5_conv3  <<<dim3(64,4), dim3(256), 0, stream>>>(out3T, A3, outF, st3);
  k_bnstat  <<<dim3(1),    dim3(64),  0, stream>>>(st3, 256, 65536.f, c3g, c3b, bn3);
  k6_final  <<<dim3(2048), dim3(256), 0, stream>>>(outF, bn3);
}